// Round 3
// baseline (322.097 us; speedup 1.0000x reference)
//
#include <hip/hip_runtime.h>
#include <hip/hip_bf16.h>
#include <hip/hip_fp16.h>

#define NN 50000
#define INCH 512
#define OUTCH 64
#define NB 196            // ceil(50000/256)
#define NTILES 3125       // 50000 / 16 (exact)

typedef __attribute__((ext_vector_type(8))) short short8;
typedef __attribute__((ext_vector_type(4))) float floatx4;

__device__ __forceinline__ unsigned short f2bf(float f) {
    unsigned u = __float_as_uint(f);
    return (unsigned short)((u + 0x7FFFu + ((u >> 16) & 1u)) >> 16);  // RNE
}

// ---------------- zero ----------------
__global__ void zero_kernel(int* __restrict__ p, int n) {
    int i = blockIdx.x * blockDim.x + threadIdx.x;
    if (i < n) p[i] = 0;
}

// ---------------- histogram of destination rows ----------------
__global__ void hist_kernel(const int* __restrict__ rows, int* __restrict__ deg, int n) {
    int e = blockIdx.x * blockDim.x + threadIdx.x;
    if (e < n) atomicAdd(&deg[rows[e]], 1);
}

// ---------------- hierarchical scan: block partial sums ----------------
__global__ __launch_bounds__(256) void partial_kernel(const int* __restrict__ deg,
                                                      int* __restrict__ bsum, int n) {
    int i = blockIdx.x * 256 + threadIdx.x;
    int v = (i < n) ? deg[i] : 0;
#pragma unroll
    for (int o = 32; o > 0; o >>= 1) v += __shfl_down(v, o, 64);
    __shared__ int ws[4];
    if ((threadIdx.x & 63) == 0) ws[threadIdx.x >> 6] = v;
    __syncthreads();
    if (threadIdx.x == 0) bsum[blockIdx.x] = ws[0] + ws[1] + ws[2] + ws[3];
}

// ---------------- scan the 196 partials (1 block) ----------------
__global__ __launch_bounds__(256) void scanpart_kernel(const int* __restrict__ bsum,
                                                       int* __restrict__ bpre,
                                                       int* __restrict__ offs, int Etot) {
    __shared__ int sd[256];
    const int t = threadIdx.x;
    int v = (t < NB) ? bsum[t] : 0;
    sd[t] = v;
    __syncthreads();
#pragma unroll
    for (int o = 1; o < 256; o <<= 1) {
        int y = (t >= o) ? sd[t - o] : 0;
        __syncthreads();
        sd[t] += y;
        __syncthreads();
    }
    if (t < NB) bpre[t] = sd[t] - v;     // exclusive
    if (t == 0) offs[NN] = Etot;
}

// ---------------- per-block rescan + add block prefix ----------------
__global__ __launch_bounds__(256) void scanfinal_kernel(const int* __restrict__ deg,
                                                        const int* __restrict__ bpre,
                                                        int* __restrict__ offs,
                                                        int* __restrict__ cursor, int n) {
    __shared__ int sd[256];
    const int t = threadIdx.x;
    const int i = blockIdx.x * 256 + t;
    int v = (i < n) ? deg[i] : 0;
    sd[t] = v;
    __syncthreads();
#pragma unroll
    for (int o = 1; o < 256; o <<= 1) {
        int y = (t >= o) ? sd[t - o] : 0;
        __syncthreads();
        sd[t] += y;
        __syncthreads();
    }
    if (i < n) {
        int ex = bpre[blockIdx.x] + sd[t] - v;
        offs[i] = ex;
        cursor[i] = ex;
    }
}

// ---------------- scatter edges into row-sorted packed array ----------------
// packed edge: low 16 bits = col (N < 65536), high 16 bits = value as fp16
__global__ void scatter_kernel(const int* __restrict__ rows, const int* __restrict__ cols,
                               const float* __restrict__ vals, int* __restrict__ cursor,
                               unsigned* __restrict__ edges, int n) {
    int e = blockIdx.x * blockDim.x + threadIdx.x;
    if (e >= n) return;
    int r = rows[e];
    int p = atomicAdd(&cursor[r], 1);
    unsigned short hv = __half_as_ushort(__float2half(vals[e]));
    edges[p] = (unsigned)cols[e] | ((unsigned)hv << 16);
}

// ---------------- dense projection: x0 = features @ W via bf16 MFMA ----------------
// W staged ONCE to LDS ([n][k] bf16, stride 520 -> conflict-free b128 reads),
// then a barrier-free K-loop: each wave owns 16 rows, A-frags straight from global.
#define WSTR 520
__global__ __launch_bounds__(256) void gemm_mfma(const float* __restrict__ A,
                                                 const float* __restrict__ B,
                                                 float* __restrict__ C) {
    __shared__ unsigned short Ws[64 * WSTR];   // 66560 B -> 2 blocks/CU
    const int t = threadIdx.x;
    const int lane = t & 63;
    const int wave = t >> 6;

    // ---- stage W: [k][n] fp32 global -> [n][k] bf16 LDS ----
    {
        const int kb = t >> 4;          // 0..15
        const int n4 = (t & 15) * 4;    // 0..60
#pragma unroll
        for (int c = 0; c < 32; ++c) {
            const int k = kb + c * 16;
            const float4 w = *(const float4*)(B + k * OUTCH + n4);
            Ws[(n4 + 0) * WSTR + k] = f2bf(w.x);
            Ws[(n4 + 1) * WSTR + k] = f2bf(w.y);
            Ws[(n4 + 2) * WSTR + k] = f2bf(w.z);
            Ws[(n4 + 3) * WSTR + k] = f2bf(w.w);
        }
    }
    __syncthreads();

    const int tile = blockIdx.x * 4 + wave;
    if (tile >= NTILES) return;
    const int rbase = tile * 16;
    const int frow = lane & 15;
    const int quad = lane >> 4;
    const float* Ap = A + (size_t)(rbase + frow) * INCH + quad * 8;

    floatx4 acc[4] = {floatx4{0,0,0,0}, floatx4{0,0,0,0}, floatx4{0,0,0,0}, floatx4{0,0,0,0}};

    float4 a0 = *(const float4*)(Ap);
    float4 a1 = *(const float4*)(Ap + 4);
    for (int c = 0; c < 16; ++c) {
        const float4 c0 = a0, c1 = a1;
        if (c < 15) {
            const float* An = Ap + (c + 1) * 32;
            a0 = *(const float4*)(An);
            a1 = *(const float4*)(An + 4);
        }
        short8 af;
        af[0] = (short)f2bf(c0.x); af[1] = (short)f2bf(c0.y);
        af[2] = (short)f2bf(c0.z); af[3] = (short)f2bf(c0.w);
        af[4] = (short)f2bf(c1.x); af[5] = (short)f2bf(c1.y);
        af[6] = (short)f2bf(c1.z); af[7] = (short)f2bf(c1.w);
        const int koff = c * 32 + quad * 8;
#pragma unroll
        for (int f = 0; f < 4; ++f) {
            const short8 bfr = *(const short8*)&Ws[(f * 16 + frow) * WSTR + koff];
            acc[f] = __builtin_amdgcn_mfma_f32_16x16x32_bf16(af, bfr, acc[f], 0, 0, 0);
        }
    }

    // C/D layout: col = lane&15 (n), row = quad*4 + reg   [m89]
#pragma unroll
    for (int f = 0; f < 4; ++f) {
#pragma unroll
        for (int reg = 0; reg < 4; ++reg) {
            C[(size_t)(rbase + quad * 4 + reg) * OUTCH + f * 16 + frow] = acc[f][reg];
        }
    }
}

// ---------------- SpMM gather: 4 rows per wave, 16 lanes x float4 per row ----------------
__global__ __launch_bounds__(256) void spmm_kernel(const int* __restrict__ offs,
                                                   const unsigned* __restrict__ edges,
                                                   const float* __restrict__ xin,
                                                   float* __restrict__ xout,
                                                   const float* __restrict__ bias) {
    const int t = threadIdx.x;
    const int lane = t & 63;
    const int sub = lane >> 4;          // row slot within wave
    const int c4 = (lane & 15) * 4;     // channel base
    const int row = blockIdx.x * 16 + (t >> 6) * 4 + sub;
    const int s = offs[row];
    const int e = offs[row + 1];
    float4 acc = make_float4(0.f, 0.f, 0.f, 0.f);
    int i = s;
    for (; i + 2 <= e; i += 2) {
        const unsigned p0 = edges[i];
        const unsigned p1 = edges[i + 1];
        const float4 x0 = *(const float4*)(xin + (size_t)(p0 & 0xFFFFu) * OUTCH + c4);
        const float4 x1 = *(const float4*)(xin + (size_t)(p1 & 0xFFFFu) * OUTCH + c4);
        const float v0 = __half2float(__ushort_as_half((unsigned short)(p0 >> 16)));
        const float v1 = __half2float(__ushort_as_half((unsigned short)(p1 >> 16)));
        acc.x = fmaf(v0, x0.x, acc.x); acc.y = fmaf(v0, x0.y, acc.y);
        acc.z = fmaf(v0, x0.z, acc.z); acc.w = fmaf(v0, x0.w, acc.w);
        acc.x = fmaf(v1, x1.x, acc.x); acc.y = fmaf(v1, x1.y, acc.y);
        acc.z = fmaf(v1, x1.z, acc.z); acc.w = fmaf(v1, x1.w, acc.w);
    }
    if (i < e) {
        const unsigned p0 = edges[i];
        const float4 x0 = *(const float4*)(xin + (size_t)(p0 & 0xFFFFu) * OUTCH + c4);
        const float v0 = __half2float(__ushort_as_half((unsigned short)(p0 >> 16)));
        acc.x = fmaf(v0, x0.x, acc.x); acc.y = fmaf(v0, x0.y, acc.y);
        acc.z = fmaf(v0, x0.z, acc.z); acc.w = fmaf(v0, x0.w, acc.w);
    }
    if (bias) {
        const float4 bv = *(const float4*)(bias + c4);
        acc.x += bv.x; acc.y += bv.y; acc.z += bv.z; acc.w += bv.w;
    }
    *(float4*)(xout + (size_t)row * OUTCH + c4) = acc;
}

extern "C" void kernel_launch(void* const* d_in, const int* in_sizes, int n_in,
                              void* d_out, int out_size, void* d_ws, size_t ws_size,
                              hipStream_t stream) {
    const int*   adj   = (const int*)d_in[0];     // [2, E]
    const float* avals = (const float*)d_in[1];   // [E]
    const float* feat  = (const float*)d_in[2];   // [N, 512]
    const float* W     = (const float*)d_in[3];   // [512, 64]
    const float* bias  = (const float*)d_in[4];   // [64]
    float* out = (float*)d_out;

    const int E_ = in_sizes[1];
    const int* rows = adj;
    const int* cols = adj + E_;

    // workspace layout (16B-aligned segments)
    float*    x0     = (float*)d_ws;                      // N*64 floats (12.8 MB)
    float*    x1     = x0 + (size_t)NN * OUTCH;           // N*64 floats (12.8 MB)
    unsigned* edges  = (unsigned*)(x1 + (size_t)NN * OUTCH);  // E u32 (3.2 MB)
    int*      deg    = (int*)(edges + E_);                // N
    int*      offs   = deg + NN;                          // N+1
    int*      cursor = offs + NN + 1;                     // N
    int*      bsum   = cursor + NN;                       // NB
    int*      bpre   = bsum + NB;                         // NB

    // ---- CSR build ----
    zero_kernel<<<(NN + 255) / 256, 256, 0, stream>>>(deg, NN);
    hist_kernel<<<(E_ + 255) / 256, 256, 0, stream>>>(rows, deg, E_);
    partial_kernel<<<NB, 256, 0, stream>>>(deg, bsum, NN);
    scanpart_kernel<<<1, 256, 0, stream>>>(bsum, bpre, offs, E_);
    scanfinal_kernel<<<NB, 256, 0, stream>>>(deg, bpre, offs, cursor, NN);
    scatter_kernel<<<(E_ + 255) / 256, 256, 0, stream>>>(rows, cols, avals, cursor, edges, E_);

    // ---- dense projection (bf16 MFMA, barrier-free K-loop) ----
    gemm_mfma<<<(NTILES + 3) / 4, 256, 0, stream>>>(feat, W, x0);

    // ---- two SpMM hops; bias fused into the last ----
    spmm_kernel<<<NN / 16, 256, 0, stream>>>(offs, edges, x0, x1, nullptr);
    spmm_kernel<<<NN / 16, 256, 0, stream>>>(offs, edges, x1, out, bias);
}